// Round 7
// baseline (1907.817 us; speedup 1.0000x reference)
//
#include <hip/hip_runtime.h>
#include <math.h>

typedef _Float16 hfrag  __attribute__((ext_vector_type(8)));  // 8 f16 = 4 VGPR (MFMA A/B)
typedef _Float16 hpack  __attribute__((ext_vector_type(4)));  // 4 f16 = 8B packed store
typedef __fp16   pkv2   __attribute__((ext_vector_type(2)));  // cvt_pkrtz return type
typedef float    accf   __attribute__((ext_vector_type(16))); // MFMA C/D

constexpr float cTB = 6.0f;
constexpr float cMB = 0.001f;
constexpr float cMD = 0.001f;

constexpr int SH = 136;   // per-wave act buffer stride (halves): 272B rows, 16B-aligned

__device__ __forceinline__ float eluf(float x)  { return x > 0.f ? x : __expf(x) - 1.f; }
__device__ __forceinline__ float sigmf(float x) { return 1.f / (1.f + __expf(-x)); }
__device__ __forceinline__ float softplusf_(float x) { return x > 20.f ? x : log1pf(__expf(x)); }

__device__ __forceinline__ hpack pk4(float a, float b, float c, float d) {
  pkv2 lo = __builtin_amdgcn_cvt_pkrtz(a, b);
  pkv2 hi = __builtin_amdgcn_cvt_pkrtz(c, d);
  hpack r;
  r[0] = (_Float16)lo[0]; r[1] = (_Float16)lo[1];
  r[2] = (_Float16)hi[0]; r[3] = (_Float16)hi[1];
  return r;
}

// ---------------- weight prep: fp32 [n][K][F] -> f16 [n][Fpad][K] ----------------
__global__ void prep_transpose(const float* __restrict__ src, _Float16* __restrict__ dst,
                               int K, int F, int Fpad, int total) {
  int idx = blockIdx.x * 256 + threadIdx.x;
  if (idx >= total) return;
  int k = idx % K;
  int f = (idx / K) % Fpad;
  int n = idx / (K * Fpad);
  float v = (f < F) ? src[(size_t)n * K * F + (size_t)k * F + f] : 0.f;
  dst[idx] = (_Float16)v;
}

// One 32x32 output tile: D[f][m] += W^T[f][k] * B[k][m], B-frags from register array.
#define GEMM_T(ACC, WBASE, T, BF, NK)                                          \
  { const _Float16* wr_ = (WBASE) + ((T) * 32 + col) * (NK);                   \
    _Pragma("unroll")                                                          \
    for (int c_ = 0; c_ < (NK) / 16; ++c_) {                                   \
      hfrag av_ = *(const hfrag*)(wr_ + c_ * 16 + q8);                         \
      ACC = __builtin_amdgcn_mfma_f32_32x32x16_f16(av_, BF[c_], ACC, 0, 0, 0); \
    } }

__global__ __launch_bounds__(256, 3) void nsf_mfma(
    const float* __restrict__ gy,   const float* __restrict__ gctx,
    const float* __restrict__ eW1,  const float* __restrict__ eb1,
    const float* __restrict__ eb2,  const float* __restrict__ eb3,
    const float* __restrict__ gib,  const float* __restrict__ gcb,
    const float* __restrict__ bb1,  const float* __restrict__ bb2,
    const float* __restrict__ bbc,  const float* __restrict__ gob,
    const _Float16* __restrict__ wE2T, const _Float16* __restrict__ wE3T,
    const _Float16* __restrict__ wCtxT, const _Float16* __restrict__ wW1T,
    const _Float16* __restrict__ wW2T,  const _Float16* __restrict__ wWcT,
    const _Float16* __restrict__ wOutT, float* __restrict__ gout)
{
  // per-wave private slice: no cross-wave sharing, ZERO __syncthreads in kernel
  __shared__ _Float16 sW[4 * 32 * SH];

  const int tid  = threadIdx.x;
  const int wid  = tid >> 6;      // wave 0..3
  const int lane = tid & 63;
  const int col  = lane & 31;     // MFMA col = local sample index
  const int q8   = (lane >> 5) * 8;
  const int q4   = (lane >> 5) * 4;
  const int ms   = blockIdx.x * 128 + wid * 32;   // this wave's sample base
  _Float16* W0   = &sW[wid * 32 * SH];

  // ---------------- embedding (all in-wave) ----------------
  {  // stage 1: fp32; lane handles sample=col, e = q*32 .. q*32+31
    const float2 c2 = *(const float2*)&gctx[(size_t)(ms + col) * 2];
    const int e0 = (lane >> 5) * 32;
    #pragma unroll
    for (int jj = 0; jj < 8; ++jj) {
      float v[4];
      #pragma unroll
      for (int r = 0; r < 4; ++r) {
        const int e = e0 + jj * 4 + r;
        v[r] = eluf(c2.x * eW1[e] + c2.y * eW1[64 + e] + eb1[e]);
      }
      *(hpack*)&W0[col * SH + e0 + jj * 4] = pk4(v[0], v[1], v[2], v[3]);
    }
  }
  {  // stage 2: 2 tiles over e-out, B from W0
    hfrag bf[4];
    #pragma unroll
    for (int c = 0; c < 4; ++c) bf[c] = *(const hfrag*)(W0 + col * SH + c * 16 + q8);
    accf a0 = {}, a1 = {};
    GEMM_T(a0, wE2T, 0, bf, 64)
    GEMM_T(a1, wE2T, 1, bf, 64)
    #pragma unroll
    for (int t = 0; t < 2; ++t) {
      accf& A = t ? a1 : a0;
      #pragma unroll
      for (int g = 0; g < 4; ++g) {
        const int e = t * 32 + 8 * g + q4;
        const float4 b = *(const float4*)&eb2[e];
        *(hpack*)&W0[col * SH + e] =
            pk4(eluf(A[4 * g + 0] + b.x), eluf(A[4 * g + 1] + b.y),
                eluf(A[4 * g + 2] + b.z), eluf(A[4 * g + 3] + b.w));
      }
    }
  }
  hfrag embf[4];   // persistent final-embedding B-frags (registers)
  {  // stage 3
    hfrag bf[4];
    #pragma unroll
    for (int c = 0; c < 4; ++c) bf[c] = *(const hfrag*)(W0 + col * SH + c * 16 + q8);
    accf a0 = {}, a1 = {};
    GEMM_T(a0, wE3T, 0, bf, 64)
    GEMM_T(a1, wE3T, 1, bf, 64)
    #pragma unroll
    for (int t = 0; t < 2; ++t) {
      accf& A = t ? a1 : a0;
      #pragma unroll
      for (int g = 0; g < 4; ++g) {
        const int e = t * 32 + 8 * g + q4;
        const float4 b = *(const float4*)&eb3[e];
        *(hpack*)&W0[col * SH + e] =
            pk4(eluf(A[4 * g + 0] + b.x), eluf(A[4 * g + 1] + b.y),
                eluf(A[4 * g + 2] + b.z), eluf(A[4 * g + 3] + b.w));
      }
    }
    #pragma unroll
    for (int c = 0; c < 4; ++c) embf[c] = *(const hfrag*)(W0 + col * SH + c * 16 + q8);
  }

  // ---------------- flow layers (wave-private, no barriers) ----------------
  float z = 0.f, lad = 0.f;
  if (lane < 32) z = gy[ms + lane];

  accf h[4];   // raw h fp32, full 128-f for this wave's 32 samples

  #pragma unroll 1
  for (int l = 0; l < 6; ++l) {
    // ---- ctx: h = init_b + ctx_b + emb @ ctx_W  (4 tiles, 2 at a time) ----
    {
      const _Float16* wb = wCtxT + (size_t)l * 8192;
      #pragma unroll
      for (int tp = 0; tp < 2; ++tp) {
        accf a0 = {}, a1 = {};
        GEMM_T(a0, wb, 2 * tp, embf, 64)
        GEMM_T(a1, wb, 2 * tp + 1, embf, 64)
        #pragma unroll
        for (int tt = 0; tt < 2; ++tt) {
          const int t = 2 * tp + tt;
          accf& A = tt ? a1 : a0;
          #pragma unroll
          for (int g = 0; g < 4; ++g) {
            const int f = t * 32 + 8 * g + q4;
            const float4 bi = *(const float4*)&gib[l * 128 + f];
            const float4 bc = *(const float4*)&gcb[l * 128 + f];
            #pragma unroll
            for (int r = 0; r < 4; ++r)
              h[t][4 * g + r] = A[4 * g + r] + (&bi.x)[r] + (&bc.x)[r];
            *(hpack*)&W0[col * SH + f] =
                pk4(eluf(h[t][4 * g + 0]), eluf(h[t][4 * g + 1]),
                    eluf(h[t][4 * g + 2]), eluf(h[t][4 * g + 3]));
          }
        }
      }
    }

    // ---- residual blocks ----
    #pragma unroll 1
    for (int jb = 0; jb < 2; ++jb) {
      const int wi = l * 2 + jb;
      {  // t1 = elu(elu(h) @ W1 + b1) -> W0
        hfrag bf[8];
        #pragma unroll
        for (int c = 0; c < 8; ++c) bf[c] = *(const hfrag*)(W0 + col * SH + c * 16 + q8);
        const _Float16* wb = wW1T + (size_t)wi * 16384;
        #pragma unroll
        for (int tp = 0; tp < 2; ++tp) {
          accf a0 = {}, a1 = {};
          GEMM_T(a0, wb, 2 * tp, bf, 128)
          GEMM_T(a1, wb, 2 * tp + 1, bf, 128)
          #pragma unroll
          for (int tt = 0; tt < 2; ++tt) {
            const int t = 2 * tp + tt;
            accf& A = tt ? a1 : a0;
            #pragma unroll
            for (int g = 0; g < 4; ++g) {
              const int f = t * 32 + 8 * g + q4;
              const float4 bv = *(const float4*)&bb1[wi * 128 + f];
              *(hpack*)&W0[col * SH + f] =
                  pk4(eluf(A[4 * g + 0] + bv.x), eluf(A[4 * g + 1] + bv.y),
                      eluf(A[4 * g + 2] + bv.z), eluf(A[4 * g + 3] + bv.w));
            }
          }
        }
      }
      {  // t2 = elu(t1)@W2 + b2 ; gate = sigmoid(emb@Wc + bc); h += t2*gate
        hfrag bf[8];
        #pragma unroll
        for (int c = 0; c < 8; ++c) bf[c] = *(const hfrag*)(W0 + col * SH + c * 16 + q8);
        const _Float16* wb2 = wW2T + (size_t)wi * 16384;
        const _Float16* wbc = wWcT + (size_t)wi * 8192;
        const bool last = (jb == 1);
        #pragma unroll
        for (int t = 0; t < 4; ++t) {   // per tile: bounded registers
          accf a2 = {}, ag = {};
          GEMM_T(a2, wb2, t, bf, 128)
          GEMM_T(ag, wbc, t, embf, 64)
          #pragma unroll
          for (int g = 0; g < 4; ++g) {
            const int f = t * 32 + 8 * g + q4;
            const float4 b2v = *(const float4*)&bb2[wi * 128 + f];
            const float4 bcv = *(const float4*)&bbc[wi * 128 + f];
            float s[4];
            #pragma unroll
            for (int r = 0; r < 4; ++r) {
              const float gate = sigmf(ag[4 * g + r] + (&bcv.x)[r]);
              const float hv = h[t][4 * g + r] + (a2[4 * g + r] + (&b2v.x)[r]) * gate;
              h[t][4 * g + r] = hv;
              s[r] = last ? hv : eluf(hv);   // last block: stage RAW h for out-GEMM
            }
            *(hpack*)&W0[col * SH + f] = pk4(s[0], s[1], s[2], s[3]);
          }
        }
      }
    }

    // ---- p = h @ out_W + out_b  (3 tiles = 96 f incl. 1 zero pad row) ----
    {
      hfrag bf[8];
      #pragma unroll
      for (int c = 0; c < 8; ++c) bf[c] = *(const hfrag*)(W0 + col * SH + c * 16 + q8);
      const _Float16* wb = wOutT + (size_t)l * 12288;
      #pragma unroll
      for (int t = 0; t < 3; ++t) {
        accf a = {};
        GEMM_T(a, wb, t, bf, 128)
        #pragma unroll
        for (int g = 0; g < 4; ++g) {
          const int f = t * 32 + 8 * g + q4;
          float s[4];
          #pragma unroll
          for (int r = 0; r < 4; ++r) {
            const float ob = (f + r < 95) ? gob[l * 95 + f + r] : 0.f;
            s[r] = a[4 * g + r] + ob;
          }
          *(hpack*)&W0[col * SH + f] = pk4(s[0], s[1], s[2], s[3]);
        }
      }
    }

    // ---- rational-quadratic spline: in-wave, lanes 0-31, p in registers ----
    if (lane < 32) {
      const float invS = 0.08838834764831845f;  // 1/sqrt(128)
      hfrag P[12];
      #pragma unroll
      for (int i = 0; i < 12; ++i)
        P[i] = *(const hfrag*)(W0 + lane * SH + i * 8);
      auto pm = [&](int i) -> float { return (float)P[i >> 3][i & 7]; };

      float mw = pm(0), mh = pm(32);
      #pragma unroll
      for (int i = 1; i < 32; ++i) {
        mw = fmaxf(mw, pm(i));
        mh = fmaxf(mh, pm(32 + i));
      }
      float sw = 0.f, sh = 0.f;
      #pragma unroll
      for (int i = 0; i < 32; ++i) {
        sw += __expf((pm(i) - mw) * invS);
        sh += __expf((pm(32 + i) - mh) * invS);
      }
      const float cw_scale = (1.0f - cMB * 32.f) / sw;
      const float ch_scale = (1.0f - cMB * 32.f) / sh;
      const float yc = fminf(fmaxf(z, -cTB), cTB);

      int idx = 0;
      float cum = 0.f, cw_k = -cTB, cw_k1 = cTB;
      bool take = true;
      #pragma unroll
      for (int i = 1; i <= 32; ++i) {
        float cwi;
        if (i < 32) {
          cum += cMB + __expf((pm(i - 1) - mw) * invS) * cw_scale;
          cwi = 2.f * cTB * cum - cTB;
        } else {
          cwi = cTB;
        }
        if (take) { cw_k1 = cwi; take = false; }
        if (i < 32 && yc >= cwi) { idx = i; cw_k = cwi; take = true; }
      }

      cum = 0.f;
      float ch_k = -cTB, ch_k1 = cTB;
      #pragma unroll
      for (int i = 1; i < 32; ++i) {
        cum += cMB + __expf((pm(32 + i - 1) - mh) * invS) * ch_scale;
        const float chi = 2.f * cTB * cum - cTB;
        if (i == idx) ch_k = chi;
        if (i == idx + 1) ch_k1 = chi;
      }

      const float w_k = cw_k1 - cw_k;
      const float h_k = ch_k1 - ch_k;
      // dynamic derivative lookups stay in LDS (avoid dynamic register indexing)
      const float dkl  = (float)W0[lane * SH + 64 + (idx > 0 ? idx - 1 : 0)];
      const float dkr  = (float)W0[lane * SH + 64 + (idx < 31 ? idx : 30)];
      const float d_k  = (idx == 0)  ? 1.f : cMD + softplusf_(dkl);
      const float d_k1 = (idx == 31) ? 1.f : cMD + softplusf_(dkr);

      const float s_k  = h_k / w_k;
      const float th   = (yc - cw_k) / w_k;
      const float th1m = th * (1.f - th);
      const float numv = h_k * (s_k * th * th + d_k * th1m);
      const float denv = s_k + (d_k + d_k1 - 2.f * s_k) * th1m;
      const float outv = ch_k + numv / denv;
      const float omt  = 1.f - th;
      const float dnum = s_k * s_k * (d_k1 * th * th + 2.f * s_k * th1m + d_k * omt * omt);
      const float ladv = __logf(dnum) - 2.f * __logf(denv);
      const bool inside = (z >= -cTB) && (z <= cTB);
      if (inside) { z = outv; lad += ladv; }
    }
  }

  if (lane < 32) {
    gout[ms + lane] = -0.5f * z * z - 0.9189385332046727f + lad;
  }
}

extern "C" void kernel_launch(void* const* d_in, const int* in_sizes, int n_in,
                              void* d_out, int out_size, void* d_ws, size_t ws_size,
                              hipStream_t stream) {
  const float* gy   = (const float*)d_in[0];
  const float* gctx = (const float*)d_in[1];
  const float* eW1  = (const float*)d_in[2];
  const float* eb1  = (const float*)d_in[3];
  const float* eW2  = (const float*)d_in[4];
  const float* eb2  = (const float*)d_in[5];
  const float* eW3  = (const float*)d_in[6];
  const float* eb3  = (const float*)d_in[7];
  const float* gib  = (const float*)d_in[8];
  const float* gcW  = (const float*)d_in[9];
  const float* gcb  = (const float*)d_in[10];
  const float* bW1  = (const float*)d_in[11];
  const float* bb1  = (const float*)d_in[12];
  const float* bW2  = (const float*)d_in[13];
  const float* bb2  = (const float*)d_in[14];
  const float* bWc  = (const float*)d_in[15];
  const float* bbc  = (const float*)d_in[16];
  const float* goW  = (const float*)d_in[17];
  const float* gob  = (const float*)d_in[18];

  _Float16* ws    = (_Float16*)d_ws;
  _Float16* wE2T  = ws;                  // 64*64
  _Float16* wE3T  = wE2T + 4096;         // 64*64
  _Float16* wCtxT = wE3T + 4096;         // 6*128*64
  _Float16* wW1T  = wCtxT + 49152;       // 12*128*128
  _Float16* wW2T  = wW1T + 196608;       // 12*128*128
  _Float16* wWcT  = wW2T + 196608;       // 12*128*64
  _Float16* wOutT = wWcT + 98304;        // 6*96*128

  auto prep = [&](const float* s, _Float16* d, int K, int F, int Fp, int n) {
    int tot = n * Fp * K;
    prep_transpose<<<(tot + 255) / 256, 256, 0, stream>>>(s, d, K, F, Fp, tot);
  };
  prep(eW2, wE2T, 64, 64, 64, 1);
  prep(eW3, wE3T, 64, 64, 64, 1);
  prep(gcW, wCtxT, 64, 128, 128, 6);
  prep(bW1, wW1T, 128, 128, 128, 12);
  prep(bW2, wW2T, 128, 128, 128, 12);
  prep(bWc, wWcT, 64, 128, 128, 12);
  prep(goW, wOutT, 128, 95, 96, 6);

  nsf_mfma<<<dim3(262144 / 128), dim3(256), 0, stream>>>(
      gy, gctx, eW1, eb1, eb2, eb3, gib, gcb, bb1, bb2, bbc, gob,
      wE2T, wE3T, wCtxT, wW1T, wW2T, wWcT, wOutT, (float*)d_out);
}

// Round 8
// 1829.164 us; speedup vs baseline: 1.0430x; 1.0430x over previous
//
#include <hip/hip_runtime.h>
#include <math.h>

typedef _Float16 hfrag  __attribute__((ext_vector_type(8)));  // 8 f16 = 4 VGPR (MFMA A/B)
typedef _Float16 hpack  __attribute__((ext_vector_type(4)));  // 4 f16 = 8B packed store
typedef __fp16   pkv2   __attribute__((ext_vector_type(2)));  // cvt_pkrtz return type
typedef float    accf   __attribute__((ext_vector_type(16))); // MFMA C/D

constexpr float cTB = 6.0f;
constexpr float cMB = 0.001f;
constexpr float cMD = 0.001f;

constexpr int SH = 136;   // act buffer stride (halves): 16B-aligned rows, bank-balanced b128
constexpr int SP = 100;   // p buffer stride (halves)

__device__ __forceinline__ float eluf(float x)  { return x > 0.f ? x : __expf(x) - 1.f; }
__device__ __forceinline__ float sigmf(float x) { return 1.f / (1.f + __expf(-x)); }
__device__ __forceinline__ float softplusf_(float x) { return x > 20.f ? x : log1pf(__expf(x)); }

__device__ __forceinline__ hpack pk4(float a, float b, float c, float d) {
  pkv2 lo = __builtin_amdgcn_cvt_pkrtz(a, b);
  pkv2 hi = __builtin_amdgcn_cvt_pkrtz(c, d);
  hpack r;
  r[0] = (_Float16)lo[0]; r[1] = (_Float16)lo[1];
  r[2] = (_Float16)hi[0]; r[3] = (_Float16)hi[1];
  return r;
}

// ---------------- weight prep: fp32 [n][K][F] -> f16 [n][Fpad][K] ----------------
__global__ void prep_transpose(const float* __restrict__ src, _Float16* __restrict__ dst,
                               int K, int F, int Fpad, int total) {
  int idx = blockIdx.x * 256 + threadIdx.x;
  if (idx >= total) return;
  int k = idx % K;
  int f = (idx / K) % Fpad;
  int n = idx / (K * Fpad);
  float v = (f < F) ? src[(size_t)n * K * F + (size_t)k * F + f] : 0.f;
  dst[idx] = (_Float16)v;
}

// GEMM over both n-tiles, B from LDS: D[f][m] += W^T[f][k] * Act^T[k][m]
#define GEMM2(WROW, BPTR, BSTRIDE, KDIM, A0, A1)                               \
  _Pragma("unroll")                                                            \
  for (int c = 0; c < (KDIM); c += 16) {                                       \
    hfrag av = *(const hfrag*)((WROW) + c + q8);                               \
    hfrag b0 = *(const hfrag*)((BPTR) + col * (BSTRIDE) + c + q8);             \
    hfrag b1 = *(const hfrag*)((BPTR) + (32 + col) * (BSTRIDE) + c + q8);      \
    A0 = __builtin_amdgcn_mfma_f32_32x32x16_f16(av, b0, A0, 0, 0, 0);          \
    A1 = __builtin_amdgcn_mfma_f32_32x32x16_f16(av, b1, A1, 0, 0, 0);          \
  }

__global__ __launch_bounds__(256, 4) void nsf_mfma(
    const float* __restrict__ gy,   const float* __restrict__ gctx,
    const float* __restrict__ eW1,  const float* __restrict__ eb1,
    const float* __restrict__ eb2,  const float* __restrict__ eb3,
    const float* __restrict__ gib,  const float* __restrict__ gcb,
    const float* __restrict__ bb1,  const float* __restrict__ bb2,
    const float* __restrict__ bbc,  const float* __restrict__ gob,
    const _Float16* __restrict__ wE2T, const _Float16* __restrict__ wE3T,
    const _Float16* __restrict__ wCtxT, const _Float16* __restrict__ wW1T,
    const _Float16* __restrict__ wW2T,  const _Float16* __restrict__ wWcT,
    const _Float16* __restrict__ wOutT, float* __restrict__ gout)
{
  __shared__ _Float16 sH[64 * SH];   // act buffer (elu(h) / raw h), [m][k]
  __shared__ _Float16 sT[64 * SH];   // act buffer (elu(t1)); aliased as p-buffer [m][SP]

  const int tid  = threadIdx.x;
  const int wid  = tid >> 6;      // wave 0..3 -> f-slice
  const int lane = tid & 63;
  const int col  = lane & 31;     // MFMA col
  const int q8   = (lane >> 5) * 8;
  const int q4   = (lane >> 5) * 4;
  const int f0   = wid * 32;
  const int m0   = blockIdx.x * 64;

  // ---------------- embedding ----------------
  {  // stage 1: fp32, 4 e-groups x 64 m -> sH (e 0..63)
    const int m  = tid & 63;
    const int eg = tid >> 6;
    const float2 c2 = *(const float2*)&gctx[(size_t)(m0 + m) * 2];
    #pragma unroll
    for (int j = 0; j < 16; ++j) {
      const int e = eg * 16 + j;
      sH[m * SH + e] = (_Float16)eluf(c2.x * eW1[e] + c2.y * eW1[64 + e] + eb1[e]);
    }
  }
  __syncthreads();
  {  // stage 2: MFMA, each wave one (ft2, nt2) tile -> sT
    const int ft2 = wid & 1, nt2 = wid >> 1;
    accf a = {};
    const _Float16* wr = wE2T + (32 * ft2 + col) * 64;
    #pragma unroll
    for (int c = 0; c < 64; c += 16) {
      hfrag av = *(const hfrag*)(wr + c + q8);
      hfrag bv = *(const hfrag*)(&sH[(nt2 * 32 + col) * SH + c + q8]);
      a = __builtin_amdgcn_mfma_f32_32x32x16_f16(av, bv, a, 0, 0, 0);
    }
    const int mr2 = nt2 * 32 + col;
    #pragma unroll
    for (int g = 0; g < 4; ++g) {
      const int e = 32 * ft2 + 8 * g + q4;
      const float4 b = *(const float4*)&eb2[e];
      *(hpack*)&sT[mr2 * SH + e] =
          pk4(eluf(a[4 * g + 0] + b.x), eluf(a[4 * g + 1] + b.y),
              eluf(a[4 * g + 2] + b.z), eluf(a[4 * g + 3] + b.w));
    }
  }
  __syncthreads();
  {  // stage 3: MFMA -> sH (final embedding)
    const int ft2 = wid & 1, nt2 = wid >> 1;
    accf a = {};
    const _Float16* wr = wE3T + (32 * ft2 + col) * 64;
    #pragma unroll
    for (int c = 0; c < 64; c += 16) {
      hfrag av = *(const hfrag*)(wr + c + q8);
      hfrag bv = *(const hfrag*)(&sT[(nt2 * 32 + col) * SH + c + q8]);
      a = __builtin_amdgcn_mfma_f32_32x32x16_f16(av, bv, a, 0, 0, 0);
    }
    const int mr2 = nt2 * 32 + col;
    #pragma unroll
    for (int g = 0; g < 4; ++g) {
      const int e = 32 * ft2 + 8 * g + q4;
      const float4 b = *(const float4*)&eb3[e];
      *(hpack*)&sH[mr2 * SH + e] =
          pk4(eluf(a[4 * g + 0] + b.x), eluf(a[4 * g + 1] + b.y),
              eluf(a[4 * g + 2] + b.z), eluf(a[4 * g + 3] + b.w));
    }
  }
  __syncthreads();

  // persistent embedding B-frags (registers) — replaces sE LDS buffer
  hfrag embf0[4], embf1[4];
  #pragma unroll
  for (int c = 0; c < 4; ++c) {
    embf0[c] = *(const hfrag*)(&sH[col * SH + c * 16 + q8]);
    embf1[c] = *(const hfrag*)(&sH[(32 + col) * SH + c * 16 + q8]);
  }
  __syncthreads();   // protect sH until all waves captured embf

  // ---------------- flow layers ----------------
  float z = 0.f, lad = 0.f;
  if (tid < 64) z = gy[m0 + tid];

  accf h0, h1;  // raw h (fp32) for this wave's f-slice, n-tiles 0/1

  for (int l = 0; l < 6; ++l) {
    // ---- ctx: h = init_b + ctx_b + emb @ ctx_W  (B from embf registers) ----
    {
      accf a0 = {}, a1 = {};
      const _Float16* wr = wCtxT + (size_t)l * 8192 + (f0 + col) * 64;
      #pragma unroll
      for (int c = 0; c < 4; ++c) {
        hfrag av = *(const hfrag*)(wr + c * 16 + q8);
        a0 = __builtin_amdgcn_mfma_f32_32x32x16_f16(av, embf0[c], a0, 0, 0, 0);
        a1 = __builtin_amdgcn_mfma_f32_32x32x16_f16(av, embf1[c], a1, 0, 0, 0);
      }
      #pragma unroll
      for (int nt = 0; nt < 2; ++nt) {
        accf& A = nt ? a1 : a0;
        accf& H = nt ? h1 : h0;
        const int mrow = nt * 32 + col;
        #pragma unroll
        for (int g = 0; g < 4; ++g) {
          const int f = f0 + 8 * g + q4;
          const float4 bi = *(const float4*)&gib[l * 128 + f];
          const float4 bc = *(const float4*)&gcb[l * 128 + f];
          #pragma unroll
          for (int r = 0; r < 4; ++r)
            H[4 * g + r] = A[4 * g + r] + (&bi.x)[r] + (&bc.x)[r];
          *(hpack*)&sH[mrow * SH + f] =
              pk4(eluf(H[4 * g + 0]), eluf(H[4 * g + 1]),
                  eluf(H[4 * g + 2]), eluf(H[4 * g + 3]));
        }
      }
    }
    __syncthreads();

    // ---- residual blocks ----
    for (int jb = 0; jb < 2; ++jb) {
      const int wi = l * 2 + jb;
      {  // t1 = elu(elu(h) @ W1 + b1) -> sT
        accf a0 = {}, a1 = {};
        const _Float16* wr = wW1T + (size_t)wi * 16384 + (f0 + col) * 128;
        GEMM2(wr, sH, SH, 128, a0, a1)
        #pragma unroll
        for (int nt = 0; nt < 2; ++nt) {
          accf& A = nt ? a1 : a0;
          const int mrow = nt * 32 + col;
          #pragma unroll
          for (int g = 0; g < 4; ++g) {
            const int f = f0 + 8 * g + q4;
            const float4 bv = *(const float4*)&bb1[wi * 128 + f];
            *(hpack*)&sT[mrow * SH + f] =
                pk4(eluf(A[4 * g + 0] + bv.x), eluf(A[4 * g + 1] + bv.y),
                    eluf(A[4 * g + 2] + bv.z), eluf(A[4 * g + 3] + bv.w));
          }
        }
      }
      __syncthreads();
      {  // t2 = elu(t1)@W2 + b2 ; gate = sigmoid(emb@Wc + bc); h += t2*gate
        // two n-tile passes: halves live accumulators (AGPR 64 -> 32)
        const _Float16* wr2 = wW2T + (size_t)wi * 16384 + (f0 + col) * 128;
        const _Float16* wrc = wWcT + (size_t)wi * 8192 + (f0 + col) * 64;
        const bool last = (jb == 1);
        #pragma unroll
        for (int nt = 0; nt < 2; ++nt) {
          accf a2 = {}, ag = {};
          #pragma unroll
          for (int c = 0; c < 8; ++c) {
            hfrag av = *(const hfrag*)(wr2 + c * 16 + q8);
            hfrag bv = *(const hfrag*)(&sT[(nt * 32 + col) * SH + c * 16 + q8]);
            a2 = __builtin_amdgcn_mfma_f32_32x32x16_f16(av, bv, a2, 0, 0, 0);
          }
          #pragma unroll
          for (int c = 0; c < 4; ++c) {
            hfrag av = *(const hfrag*)(wrc + c * 16 + q8);
            ag = __builtin_amdgcn_mfma_f32_32x32x16_f16(
                av, nt ? embf1[c] : embf0[c], ag, 0, 0, 0);
          }
          accf& H = nt ? h1 : h0;
          const int mrow = nt * 32 + col;
          #pragma unroll
          for (int g = 0; g < 4; ++g) {
            const int f = f0 + 8 * g + q4;
            const float4 b2v = *(const float4*)&bb2[wi * 128 + f];
            const float4 bcv = *(const float4*)&bbc[wi * 128 + f];
            float s[4];
            #pragma unroll
            for (int r = 0; r < 4; ++r) {
              const float gate = sigmf(ag[4 * g + r] + (&bcv.x)[r]);
              const float hv = H[4 * g + r] + (a2[4 * g + r] + (&b2v.x)[r]) * gate;
              H[4 * g + r] = hv;
              s[r] = last ? hv : eluf(hv);   // last block: stage RAW h for out-GEMM
            }
            *(hpack*)&sH[mrow * SH + f] = pk4(s[0], s[1], s[2], s[3]);
          }
        }
      }
      __syncthreads();
    }

    // ---- p = h @ out_W + out_b  (waves 0-2: F=96 incl. 1 zero pad row) ----
    if (wid < 3) {
      accf a0 = {}, a1 = {};
      const _Float16* wr = wOutT + (size_t)l * 12288 + (f0 + col) * 128;
      GEMM2(wr, sH, SH, 128, a0, a1)
      #pragma unroll
      for (int nt = 0; nt < 2; ++nt) {
        accf& A = nt ? a1 : a0;
        const int mrow = nt * 32 + col;
        #pragma unroll
        for (int g = 0; g < 4; ++g) {
          const int f = f0 + 8 * g + q4;
          float s[4];
          #pragma unroll
          for (int r = 0; r < 4; ++r) {
            const float ob = (f + r < 95) ? gob[l * 95 + f + r] : 0.f;
            s[r] = A[4 * g + r] + ob;
          }
          *(hpack*)&sT[mrow * SP + f] = pk4(s[0], s[1], s[2], s[3]);
        }
      }
    }
    __syncthreads();

    // ---- rational-quadratic spline: wave 0, one lane per sample ----
    // (overlaps with waves 1-3 running next layer's ctx-GEMM; t1's sT write
    //  is behind the post-ctx barrier which wave 0 reaches only after this)
    if (tid < 64) {
      const float invS = 0.08838834764831845f;  // 1/sqrt(128)
      const _Float16* pmv = &sT[tid * SP];
      auto pm = [&](int i) -> float { return (float)pmv[i]; };
      float mw = pm(0), mh = pm(32);
      #pragma unroll
      for (int i = 1; i < 32; ++i) {
        mw = fmaxf(mw, pm(i));
        mh = fmaxf(mh, pm(32 + i));
      }
      float sw = 0.f, sh = 0.f;
      #pragma unroll
      for (int i = 0; i < 32; ++i) {
        sw += __expf((pm(i) - mw) * invS);
        sh += __expf((pm(32 + i) - mh) * invS);
      }
      const float cw_scale = (1.0f - cMB * 32.f) / sw;
      const float ch_scale = (1.0f - cMB * 32.f) / sh;
      const float yc = fminf(fmaxf(z, -cTB), cTB);

      int idx = 0;
      float cum = 0.f, cw_k = -cTB, cw_k1 = cTB;
      bool take = true;
      #pragma unroll
      for (int i = 1; i <= 32; ++i) {
        float cwi;
        if (i < 32) {
          cum += cMB + __expf((pm(i - 1) - mw) * invS) * cw_scale;
          cwi = 2.f * cTB * cum - cTB;
        } else {
          cwi = cTB;
        }
        if (take) { cw_k1 = cwi; take = false; }
        if (i < 32 && yc >= cwi) { idx = i; cw_k = cwi; take = true; }
      }

      cum = 0.f;
      float ch_k = -cTB, ch_k1 = cTB;
      #pragma unroll
      for (int i = 1; i < 32; ++i) {
        cum += cMB + __expf((pm(32 + i - 1) - mh) * invS) * ch_scale;
        const float chi = 2.f * cTB * cum - cTB;
        if (i == idx) ch_k = chi;
        if (i == idx + 1) ch_k1 = chi;
      }

      const float w_k = cw_k1 - cw_k;
      const float h_k = ch_k1 - ch_k;
      const float d_k  = (idx == 0)  ? 1.f : cMD + softplusf_(pm(64 + idx - 1));
      const float d_k1 = (idx == 31) ? 1.f : cMD + softplusf_(pm(64 + idx));

      const float s_k  = h_k / w_k;
      const float th   = (yc - cw_k) / w_k;
      const float th1m = th * (1.f - th);
      const float numv = h_k * (s_k * th * th + d_k * th1m);
      const float denv = s_k + (d_k + d_k1 - 2.f * s_k) * th1m;
      const float outv = ch_k + numv / denv;
      const float omt  = 1.f - th;
      const float dnum = s_k * s_k * (d_k1 * th * th + 2.f * s_k * th1m + d_k * omt * omt);
      const float ladv = __logf(dnum) - 2.f * __logf(denv);
      const bool inside = (z >= -cTB) && (z <= cTB);
      if (inside) { z = outv; lad += ladv; }
    }
  }

  if (tid < 64) {
    gout[m0 + tid] = -0.5f * z * z - 0.9189385332046727f + lad;
  }
}

extern "C" void kernel_launch(void* const* d_in, const int* in_sizes, int n_in,
                              void* d_out, int out_size, void* d_ws, size_t ws_size,
                              hipStream_t stream) {
  const float* gy   = (const float*)d_in[0];
  const float* gctx = (const float*)d_in[1];
  const float* eW1  = (const float*)d_in[2];
  const float* eb1  = (const float*)d_in[3];
  const float* eW2  = (const float*)d_in[4];
  const float* eb2  = (const float*)d_in[5];
  const float* eW3  = (const float*)d_in[6];
  const float* eb3  = (const float*)d_in[7];
  const float* gib  = (const float*)d_in[8];
  const float* gcW  = (const float*)d_in[9];
  const float* gcb  = (const float*)d_in[10];
  const float* bW1  = (const float*)d_in[11];
  const float* bb1  = (const float*)d_in[12];
  const float* bW2  = (const float*)d_in[13];
  const float* bb2  = (const float*)d_in[14];
  const float* bWc  = (const float*)d_in[15];
  const float* bbc  = (const float*)d_in[16];
  const float* goW  = (const float*)d_in[17];
  const float* gob  = (const float*)d_in[18];

  _Float16* ws    = (_Float16*)d_ws;
  _Float16* wE2T  = ws;                  // 64*64
  _Float16* wE3T  = wE2T + 4096;         // 64*64
  _Float16* wCtxT = wE3T + 4096;         // 6*128*64
  _Float16* wW1T  = wCtxT + 49152;       // 12*128*128
  _Float16* wW2T  = wW1T + 196608;       // 12*128*128
  _Float16* wWcT  = wW2T + 196608;       // 12*128*64
  _Float16* wOutT = wWcT + 98304;        // 6*96*128

  auto prep = [&](const float* s, _Float16* d, int K, int F, int Fp, int n) {
    int tot = n * Fp * K;
    prep_transpose<<<(tot + 255) / 256, 256, 0, stream>>>(s, d, K, F, Fp, tot);
  };
  prep(eW2, wE2T, 64, 64, 64, 1);
  prep(eW3, wE3T, 64, 64, 64, 1);
  prep(gcW, wCtxT, 64, 128, 128, 6);
  prep(bW1, wW1T, 128, 128, 128, 12);
  prep(bW2, wW2T, 128, 128, 128, 12);
  prep(bWc, wWcT, 64, 128, 128, 12);
  prep(goW, wOutT, 128, 95, 96, 6);

  nsf_mfma<<<dim3(262144 / 64), dim3(256), 0, stream>>>(
      gy, gctx, eW1, eb1, eb2, eb3, gib, gcb, bb1, bb2, bbc, gob,
      wE2T, wE3T, wCtxT, wW1T, wW2T, wWcT, wOutT, (float*)d_out);
}